// Round 2
// baseline (857.656 us; speedup 1.0000x reference)
//
#include <hip/hip_runtime.h>

#define NU_N 100000
#define NI_N 50000
#define E_N  500000
#define NSEL 8192

typedef short s8v __attribute__((ext_vector_type(8)));
typedef float f4v __attribute__((ext_vector_type(4)));

__device__ __forceinline__ float bf2f(unsigned short h) {
  union { unsigned u; float f; } v; v.u = ((unsigned)h) << 16; return v.f;
}
__device__ __forceinline__ unsigned short f2bf(float f) {
  union { float f; unsigned u; } v; v.f = f;
  unsigned u = v.u;
  u += 0x7FFFu + ((u >> 16) & 1u);   // round-to-nearest-even
  return (unsigned short)(u >> 16);
}

// ---------------- small utility kernels ----------------

__global__ void k_cvt8(const float* __restrict__ in, unsigned short* __restrict__ out, int n) {
  int t = blockIdx.x * blockDim.x + threadIdx.x;
  int i = t * 8;
  if (i >= n) return;
  float4 a = *(const float4*)(in + i);
  float4 b = *(const float4*)(in + i + 4);
  s8v o;
  o[0] = (short)f2bf(a.x); o[1] = (short)f2bf(a.y);
  o[2] = (short)f2bf(a.z); o[3] = (short)f2bf(a.w);
  o[4] = (short)f2bf(b.x); o[5] = (short)f2bf(b.y);
  o[6] = (short)f2bf(b.z); o[7] = (short)f2bf(b.w);
  *(s8v*)(out + i) = o;
}

__global__ void k_deg(const int* __restrict__ u_idx, const int* __restrict__ i_idx,
                      int* __restrict__ deg_u, int* __restrict__ deg_i) {
  int e = blockIdx.x * blockDim.x + threadIdx.x;
  if (e < E_N) {
    atomicAdd(deg_u + u_idx[e], 1);
    atomicAdd(deg_i + i_idx[e], 1);
  }
}

__global__ void k_norm(const int* __restrict__ u_idx, const int* __restrict__ i_idx,
                       const int* __restrict__ deg_u, const int* __restrict__ deg_i,
                       float* __restrict__ nv) {
  int e = blockIdx.x * blockDim.x + threadIdx.x;
  if (e < E_N) {
    float p = (float)deg_u[u_idx[e]] * (float)deg_i[i_idx[e]];
    nv[e] = 1.0f / sqrtf(p);
  }
}

// ---------------- B-fragment loader (W is 64x64 bf16, row-major [k][n]) ----------------
// mfma_f32_16x16x32_bf16 B layout: n = lane&15, k = 8*(lane>>4)+j
__device__ __forceinline__ void load_bfrags(const unsigned short* __restrict__ wb, s8v bf[4][2]) {
  int lane = threadIdx.x & 63;
  int lm = lane & 15, lq = lane >> 4;
#pragma unroll
  for (int n = 0; n < 4; n++)
#pragma unroll
    for (int kh = 0; kh < 2; kh++) {
      s8v f;
#pragma unroll
      for (int j = 0; j < 8; j++)
        f[j] = (short)wb[(32 * kh + 8 * lq + j) * 64 + 16 * n + lm];
      bf[n][kh] = f;
    }
}

// ---------------- projection: dst = bf16( src @ W + b ) ----------------
__global__ void k_proj(const unsigned short* __restrict__ src, unsigned short* __restrict__ dst,
                       const unsigned short* __restrict__ wb, const float* __restrict__ bias, int M) {
  s8v bf[4][2];
  load_bfrags(wb, bf);
  int lane = threadIdx.x & 63;
  int lm = lane & 15, lq = lane >> 4;
  int wid = (blockIdx.x * blockDim.x + threadIdx.x) >> 6;
  int nw  = (gridDim.x * blockDim.x) >> 6;
  int nbatch = (M + 15) >> 4;
  float bcol[4];
#pragma unroll
  for (int n = 0; n < 4; n++) bcol[n] = bias[16 * n + lm];
  for (int b = wid; b < nbatch; b += nw) {
    int m0 = b << 4;
    int row = m0 + lm;
    int rc = row < M ? row : M - 1;
    s8v a0 = *(const s8v*)(src + (size_t)rc * 64 + 8 * lq);
    s8v a1 = *(const s8v*)(src + (size_t)rc * 64 + 32 + 8 * lq);
    f4v c[4];
#pragma unroll
    for (int n = 0; n < 4; n++) c[n] = (f4v){0.f, 0.f, 0.f, 0.f};
#pragma unroll
    for (int n = 0; n < 4; n++) {
      c[n] = __builtin_amdgcn_mfma_f32_16x16x32_bf16(a0, bf[n][0], c[n], 0, 0, 0);
      c[n] = __builtin_amdgcn_mfma_f32_16x16x32_bf16(a1, bf[n][1], c[n], 0, 0, 0);
    }
#pragma unroll
    for (int n = 0; n < 4; n++)
#pragma unroll
      for (int r = 0; r < 4; r++) {
        int ro = m0 + 4 * lq + r;
        if (ro < M) dst[(size_t)ro * 64 + 16 * n + lm] = f2bf(c[n][r] + bcol[n]);
      }
  }
}

// ---------------- edge kernel: pw = (hu[u]*hi[i]) @ W2 + b2; scatter messages ----------------
__global__ void k_edge(const unsigned short* __restrict__ hu, const unsigned short* __restrict__ hi,
                       const unsigned short* __restrict__ pu, const unsigned short* __restrict__ pi,
                       const unsigned short* __restrict__ w2b, const float* __restrict__ b2,
                       const int* __restrict__ u_idx, const int* __restrict__ i_idx,
                       const float* __restrict__ nv,
                       float* __restrict__ acc_u, float* __restrict__ acc_i) {
  s8v bf[4][2];
  load_bfrags(w2b, bf);
  int lane = threadIdx.x & 63;
  int lm = lane & 15, lq = lane >> 4;
  int wid = (blockIdx.x * blockDim.x + threadIdx.x) >> 6;
  int nw  = (gridDim.x * blockDim.x) >> 6;
  int nbatch = (E_N + 15) >> 4;
  float bcol[4];
#pragma unroll
  for (int n = 0; n < 4; n++) bcol[n] = b2[16 * n + lm];
  for (int b = wid; b < nbatch; b += nw) {
    int e0 = b << 4;
    int ea = e0 + lm;
    int ec = ea < E_N ? ea : E_N - 1;
    int u = u_idx[ec], i = i_idx[ec];
    s8v xu0 = *(const s8v*)(hu + (size_t)u * 64 + 8 * lq);
    s8v xu1 = *(const s8v*)(hu + (size_t)u * 64 + 32 + 8 * lq);
    s8v xi0 = *(const s8v*)(hi + (size_t)i * 64 + 8 * lq);
    s8v xi1 = *(const s8v*)(hi + (size_t)i * 64 + 32 + 8 * lq);
    s8v a0, a1;
#pragma unroll
    for (int j = 0; j < 8; j++) {
      a0[j] = (short)f2bf(bf2f((unsigned short)xu0[j]) * bf2f((unsigned short)xi0[j]));
      a1[j] = (short)f2bf(bf2f((unsigned short)xu1[j]) * bf2f((unsigned short)xi1[j]));
    }
    f4v c[4];
#pragma unroll
    for (int n = 0; n < 4; n++) c[n] = (f4v){0.f, 0.f, 0.f, 0.f};
#pragma unroll
    for (int n = 0; n < 4; n++) {
      c[n] = __builtin_amdgcn_mfma_f32_16x16x32_bf16(a0, bf[n][0], c[n], 0, 0, 0);
      c[n] = __builtin_amdgcn_mfma_f32_16x16x32_bf16(a1, bf[n][1], c[n], 0, 0, 0);
    }
    // C layout: col j = 16n + (lane&15); edge-row = 4*(lane>>4) + r
#pragma unroll
    for (int r = 0; r < 4; r++) {
      int el = e0 + 4 * lq + r;
      bool v = el < E_N;
      int ec2 = v ? el : 0;
      int u2 = u_idx[ec2], i2 = i_idx[ec2];
      float nm = v ? nv[ec2] : 0.0f;
#pragma unroll
      for (int n = 0; n < 4; n++) {
        int j = 16 * n + lm;
        float pw = c[n][r] + bcol[n];
        float m_u2i = nm * (bf2f(pu[(size_t)u2 * 64 + j]) + pw);
        float m_i2u = nm * (bf2f(pi[(size_t)i2 * 64 + j]) + pw);
        if (v) {
          atomicAdd(acc_i + (size_t)i2 * 64 + j, m_u2i);
          atomicAdd(acc_u + (size_t)u2 * 64 + j, m_i2u);
        }
      }
    }
  }
}

// ---------------- node update: h = l2norm(leaky_relu(p + acc)) ----------------
__global__ void k_node(const unsigned short* __restrict__ pu, const float* __restrict__ acc_u,
                       unsigned short* __restrict__ hu,
                       const unsigned short* __restrict__ pi, const float* __restrict__ acc_i,
                       unsigned short* __restrict__ hi) {
  int lane = threadIdx.x & 63;
  int wid = (blockIdx.x * blockDim.x + threadIdx.x) >> 6;
  if (wid >= NU_N + NI_N) return;
  const unsigned short* p; const float* a; unsigned short* h; size_t r;
  if (wid < NU_N) { p = pu; a = acc_u; h = hu; r = (size_t)wid; }
  else            { p = pi; a = acc_i; h = hi; r = (size_t)(wid - NU_N); }
  size_t o = r * 64 + lane;
  float x = bf2f(p[o]) + a[o];
  x = x > 0.0f ? x : 0.2f * x;
  float s = x * x;
#pragma unroll
  for (int off = 32; off; off >>= 1) s += __shfl_xor(s, off);
  float d = fmaxf(sqrtf(s), 1e-12f);
  h[o] = f2bf(x / d);
}

// ---------------- output gather for layer slice l ----------------
__global__ void k_out(const float* __restrict__ fu, const float* __restrict__ fi,
                      const unsigned short* __restrict__ hu, const unsigned short* __restrict__ hi,
                      const int* __restrict__ users, const int* __restrict__ pos,
                      const int* __restrict__ neg, float* __restrict__ out, int l) {
  int t = blockIdx.x * blockDim.x + threadIdx.x;
  if (t >= 3 * NSEL * 64) return;
  int j = t & 63;
  int row = (t >> 6) & (NSEL - 1);
  int grp = t >> 19;  // 6 + 13
  int sr = grp == 0 ? users[row] : (grp == 1 ? pos[row] : neg[row]);
  float v;
  if (grp == 0) v = (l == 0) ? fu[(size_t)sr * 64 + j] : bf2f(hu[(size_t)sr * 64 + j]);
  else          v = (l == 0) ? fi[(size_t)sr * 64 + j] : bf2f(hi[(size_t)sr * 64 + j]);
  out[(size_t)grp * NSEL * 256 + (size_t)row * 256 + (size_t)l * 64 + j] = v;
}

// ---------------- host launcher ----------------
extern "C" void kernel_launch(void* const* d_in, const int* in_sizes, int n_in,
                              void* d_out, int out_size, void* d_ws, size_t ws_size,
                              hipStream_t stream) {
  (void)in_sizes; (void)n_in; (void)out_size; (void)ws_size;
  const float* fu = (const float*)d_in[0];
  const float* fi = (const float*)d_in[1];
  const float* W1 = (const float*)d_in[2];
  const float* b1 = (const float*)d_in[3];
  const float* W2 = (const float*)d_in[4];
  const float* b2 = (const float*)d_in[5];
  const int* u_idx = (const int*)d_in[6];
  const int* i_idx = (const int*)d_in[7];
  const int* users = (const int*)d_in[8];
  const int* pos   = (const int*)d_in[9];
  const int* neg   = (const int*)d_in[10];
  float* out = (float*)d_out;

  char* w = (char*)d_ws;
  auto alloc = [&](size_t bytes) { char* p = w; w += (bytes + 255) & ~(size_t)255; return p; };
  unsigned short* hu_b = (unsigned short*)alloc((size_t)NU_N * 64 * 2);
  unsigned short* hi_b = (unsigned short*)alloc((size_t)NI_N * 64 * 2);
  unsigned short* pu_b = (unsigned short*)alloc((size_t)NU_N * 64 * 2);
  unsigned short* pi_b = (unsigned short*)alloc((size_t)NI_N * 64 * 2);
  // acc_u/acc_i: ONE allocation so the single memset exactly covers both
  float* acc_u = (float*)alloc((size_t)(NU_N + NI_N) * 64 * 4);
  float* acc_i = acc_u + (size_t)NU_N * 64;
  // deg_u/deg_i: ONE allocation (bug fix: separate allocs got 256B-padded apart,
  // leaving the tail of deg_i outside the memset -> garbage degrees -> NaN/0.77)
  int* deg_u = (int*)alloc((size_t)(NU_N + NI_N) * 4);
  int* deg_i = deg_u + NU_N;
  float* nv = (float*)alloc((size_t)E_N * 4);
  unsigned short* w1b = (unsigned short*)alloc((size_t)3 * 4096 * 2);
  unsigned short* w2b = (unsigned short*)alloc((size_t)3 * 4096 * 2);

  hipMemsetAsync(deg_u, 0, (size_t)(NU_N + NI_N) * 4, stream);
  k_deg<<<(E_N + 255) / 256, 256, 0, stream>>>(u_idx, i_idx, deg_u, deg_i);
  k_norm<<<(E_N + 255) / 256, 256, 0, stream>>>(u_idx, i_idx, deg_u, deg_i, nv);
  k_cvt8<<<(NU_N * 64 / 8 + 255) / 256, 256, 0, stream>>>(fu, hu_b, NU_N * 64);
  k_cvt8<<<(NI_N * 64 / 8 + 255) / 256, 256, 0, stream>>>(fi, hi_b, NI_N * 64);
  k_cvt8<<<(3 * 4096 / 8 + 255) / 256, 256, 0, stream>>>(W1, w1b, 3 * 4096);
  k_cvt8<<<(3 * 4096 / 8 + 255) / 256, 256, 0, stream>>>(W2, w2b, 3 * 4096);
  k_out<<<(3 * NSEL * 64 + 255) / 256, 256, 0, stream>>>(fu, fi, (const unsigned short*)nullptr,
                                                         (const unsigned short*)nullptr,
                                                         users, pos, neg, out, 0);

  for (int l = 0; l < 3; l++) {
    hipMemsetAsync(acc_u, 0, (size_t)(NU_N + NI_N) * 64 * 4, stream);
    k_proj<<<512, 256, 0, stream>>>(hu_b, pu_b, w1b + (size_t)l * 4096, b1 + (size_t)l * 64, NU_N);
    k_proj<<<256, 256, 0, stream>>>(hi_b, pi_b, w1b + (size_t)l * 4096, b1 + (size_t)l * 64, NI_N);
    k_edge<<<1024, 256, 0, stream>>>(hu_b, hi_b, pu_b, pi_b, w2b + (size_t)l * 4096,
                                     b2 + (size_t)l * 64, u_idx, i_idx, nv, acc_u, acc_i);
    k_node<<<(NU_N + NI_N) / 4, 256, 0, stream>>>(pu_b, acc_u, hu_b, pi_b, acc_i, hi_b);
    k_out<<<(3 * NSEL * 64 + 255) / 256, 256, 0, stream>>>(fu, fi, hu_b, hi_b, users, pos, neg,
                                                           out, l + 1);
  }
}

// Round 3
// 535.523 us; speedup vs baseline: 1.6015x; 1.6015x over previous
//
#include <hip/hip_runtime.h>

#define NU_N 100000
#define NI_N 50000
#define NN_N 150000          // NU+NI combined nodes
#define E_N  500000
#define NSEL 8192
#define SCAN_BLOCK 256
#define SCAN_ITEMS 1024
#define SCAN_NB ((NN_N + SCAN_ITEMS - 1) / SCAN_ITEMS)   // 147

typedef short s8v __attribute__((ext_vector_type(8)));
typedef float f4v __attribute__((ext_vector_type(4)));

__device__ __forceinline__ float bf2f(unsigned short h) {
  union { unsigned u; float f; } v; v.u = ((unsigned)h) << 16; return v.f;
}
__device__ __forceinline__ unsigned short f2bf(float f) {
  union { float f; unsigned u; } v; v.f = f;
  unsigned u = v.u;
  u += 0x7FFFu + ((u >> 16) & 1u);   // round-to-nearest-even
  return (unsigned short)(u >> 16);
}

// ---------------- fp32 -> bf16 bulk convert ----------------
__global__ void k_cvt8(const float* __restrict__ in, unsigned short* __restrict__ out, int n) {
  int t = blockIdx.x * blockDim.x + threadIdx.x;
  int i = t * 8;
  if (i >= n) return;
  float4 a = *(const float4*)(in + i);
  float4 b = *(const float4*)(in + i + 4);
  s8v o;
  o[0] = (short)f2bf(a.x); o[1] = (short)f2bf(a.y);
  o[2] = (short)f2bf(a.z); o[3] = (short)f2bf(a.w);
  o[4] = (short)f2bf(b.x); o[5] = (short)f2bf(b.y);
  o[6] = (short)f2bf(b.z); o[7] = (short)f2bf(b.w);
  *(s8v*)(out + i) = o;
}

// ---------------- degree (combined node id space) ----------------
__global__ void k_deg(const int* __restrict__ u_idx, const int* __restrict__ i_idx,
                      int* __restrict__ deg) {
  int e = blockIdx.x * blockDim.x + threadIdx.x;
  if (e < E_N) {
    atomicAdd(deg + u_idx[e], 1);
    atomicAdd(deg + NU_N + i_idx[e], 1);
  }
}

__global__ void k_rdeg(const int* __restrict__ deg, float* __restrict__ rdeg) {
  int g = blockIdx.x * blockDim.x + threadIdx.x;
  if (g < NN_N) {
    int d = deg[g];
    rdeg[g] = d > 0 ? 1.0f / sqrtf((float)d) : 0.0f;
  }
}

// ---------------- 3-kernel exclusive scan of deg -> offs ----------------
__global__ void k_scan1(const int* __restrict__ deg, int* __restrict__ offs,
                        int* __restrict__ sums) {
  __shared__ int lds[SCAN_BLOCK];
  int b = blockIdx.x, t = threadIdx.x;
  int base = b * SCAN_ITEMS + t * 4;
  int v[4]; int s = 0;
#pragma unroll
  for (int k = 0; k < 4; k++) {
    int idx = base + k;
    v[k] = idx < NN_N ? deg[idx] : 0;
    s += v[k];
  }
  lds[t] = s;
  __syncthreads();
  for (int off = 1; off < SCAN_BLOCK; off <<= 1) {
    int o = t >= off ? lds[t - off] : 0;
    __syncthreads();
    lds[t] += o;
    __syncthreads();
  }
  int run = lds[t] - s;   // exclusive prefix of this thread
#pragma unroll
  for (int k = 0; k < 4; k++) {
    int idx = base + k;
    if (idx < NN_N) offs[idx] = run;
    run += v[k];
  }
  if (t == SCAN_BLOCK - 1) sums[b] = lds[t];
}

__global__ void k_scan2(int* __restrict__ sums) {
  __shared__ int lds[SCAN_BLOCK];
  int t = threadIdx.x;
  int v = t < SCAN_NB ? sums[t] : 0;
  lds[t] = v;
  __syncthreads();
  for (int off = 1; off < SCAN_BLOCK; off <<= 1) {
    int o = t >= off ? lds[t - off] : 0;
    __syncthreads();
    lds[t] += o;
    __syncthreads();
  }
  if (t < SCAN_NB) sums[t] = lds[t] - v;   // exclusive block base
}

__global__ void k_scan3(int* __restrict__ offs, const int* __restrict__ sums,
                        int* __restrict__ cur) {
  int idx = blockIdx.x * blockDim.x + threadIdx.x;
  if (idx < NN_N) {
    int o = offs[idx] + sums[idx >> 10];
    offs[idx] = o;
    cur[idx] = o;
  }
}

// ---------------- CSR fill (both directions, combined id space) ----------------
__global__ void k_fill(const int* __restrict__ u_idx, const int* __restrict__ i_idx,
                       const float* __restrict__ rdeg, int* __restrict__ cur,
                       int* __restrict__ nbr, float* __restrict__ wgt) {
  int e = blockIdx.x * blockDim.x + threadIdx.x;
  if (e >= E_N) return;
  int u = u_idx[e], gi = NU_N + i_idx[e];
  float w = rdeg[u] * rdeg[gi];
  int s1 = atomicAdd(cur + u, 1);
  nbr[s1] = gi; wgt[s1] = w;
  int s2 = atomicAdd(cur + gi, 1);
  nbr[s2] = u;  wgt[s2] = w;
}

// ---------------- weighted neighbor gather: s[g] = sum w*h[nbr], csum[g] = sum w ----------------
__global__ void k_gather(const unsigned short* __restrict__ h,
                         const int* __restrict__ offs, const int* __restrict__ deg,
                         const int* __restrict__ nbr, const float* __restrict__ wgt,
                         unsigned short* __restrict__ s, float* __restrict__ csum) {
  int wid = (blockIdx.x * blockDim.x + threadIdx.x) >> 6;
  int lane = threadIdx.x & 63;
  if (wid >= NN_N) return;
  int k0 = offs[wid], k1 = k0 + deg[wid];
  float acc = 0.f, c = 0.f;
  if (k0 < k1) {
    int nb = nbr[k0]; float w = wgt[k0];
    for (int k = k0 + 1; k < k1; k++) {
      int nb2 = nbr[k]; float w2 = wgt[k];          // prefetch next
      acc += w * bf2f(h[(size_t)nb * 64 + lane]);
      c += w;
      nb = nb2; w = w2;
    }
    acc += w * bf2f(h[(size_t)nb * 64 + lane]);
    c += w;
  }
  s[(size_t)wid * 64 + lane] = f2bf(acc);
  if (lane == 0) csum[wid] = c;
}

// ---------------- B-fragment loader (W is 64x64 bf16, row-major [k][n]) ----------------
// mfma_f32_16x16x32_bf16 B layout: n = lane&15, k = 8*(lane>>4)+j
__device__ __forceinline__ void load_bfrags(const unsigned short* __restrict__ wb, s8v bf[4][2]) {
  int lane = threadIdx.x & 63;
  int lm = lane & 15, lq = lane >> 4;
#pragma unroll
  for (int n = 0; n < 4; n++)
#pragma unroll
    for (int kh = 0; kh < 2; kh++) {
      s8v f;
#pragma unroll
      for (int j = 0; j < 8; j++)
        f[j] = (short)wb[(32 * kh + 8 * lq + j) * 64 + 16 * n + lm];
      bf[n][kh] = f;
    }
}

// ---------------- fused node update ----------------
// h = l2norm(leaky( (h+s)@W1 + (1+c)b1 + (h*s)@W2 + c*b2 ))   (in place, per 16-row tile)
__global__ void k_update(unsigned short* __restrict__ h, const unsigned short* __restrict__ s,
                         const float* __restrict__ csum,
                         const unsigned short* __restrict__ w1b, const unsigned short* __restrict__ w2b,
                         const float* __restrict__ b1, const float* __restrict__ b2) {
  s8v f1[4][2], f2w[4][2];
  load_bfrags(w1b, f1);
  load_bfrags(w2b, f2w);
  int lane = threadIdx.x & 63;
  int lm = lane & 15, lq = lane >> 4;
  int tile = (blockIdx.x * blockDim.x + threadIdx.x) >> 6;
  if (tile >= NN_N / 16) return;
  int m0 = tile << 4;
  size_t rowo = (size_t)(m0 + lm) * 64;
  s8v h0 = *(const s8v*)(h + rowo + 8 * lq);
  s8v h1 = *(const s8v*)(h + rowo + 32 + 8 * lq);
  s8v s0 = *(const s8v*)(s + rowo + 8 * lq);
  s8v s1 = *(const s8v*)(s + rowo + 32 + 8 * lq);
  s8v a10, a11, a20, a21;
#pragma unroll
  for (int j = 0; j < 8; j++) {
    float hv0 = bf2f((unsigned short)h0[j]), sv0 = bf2f((unsigned short)s0[j]);
    float hv1 = bf2f((unsigned short)h1[j]), sv1 = bf2f((unsigned short)s1[j]);
    a10[j] = (short)f2bf(hv0 + sv0); a20[j] = (short)f2bf(hv0 * sv0);
    a11[j] = (short)f2bf(hv1 + sv1); a21[j] = (short)f2bf(hv1 * sv1);
  }
  f4v c[4];
#pragma unroll
  for (int n = 0; n < 4; n++) c[n] = (f4v){0.f, 0.f, 0.f, 0.f};
#pragma unroll
  for (int n = 0; n < 4; n++) {
    c[n] = __builtin_amdgcn_mfma_f32_16x16x32_bf16(a10, f1[n][0], c[n], 0, 0, 0);
    c[n] = __builtin_amdgcn_mfma_f32_16x16x32_bf16(a11, f1[n][1], c[n], 0, 0, 0);
    c[n] = __builtin_amdgcn_mfma_f32_16x16x32_bf16(a20, f2w[n][0], c[n], 0, 0, 0);
    c[n] = __builtin_amdgcn_mfma_f32_16x16x32_bf16(a21, f2w[n][1], c[n], 0, 0, 0);
  }
  float b1c[4], b2c[4];
#pragma unroll
  for (int n = 0; n < 4; n++) { b1c[n] = b1[16 * n + lm]; b2c[n] = b2[16 * n + lm]; }
  float cm[4];
#pragma unroll
  for (int r = 0; r < 4; r++) cm[r] = csum[m0 + 4 * lq + r];
  float x[4][4], ss[4] = {0.f, 0.f, 0.f, 0.f};
#pragma unroll
  for (int n = 0; n < 4; n++)
#pragma unroll
    for (int r = 0; r < 4; r++) {
      float v = c[n][r] + b1c[n] + cm[r] * (b1c[n] + b2c[n]);
      v = v > 0.0f ? v : 0.2f * v;
      x[n][r] = v;
      ss[r] += v * v;
    }
#pragma unroll
  for (int r = 0; r < 4; r++) {
#pragma unroll
    for (int off = 1; off < 16; off <<= 1) ss[r] += __shfl_xor(ss[r], off);
    ss[r] = 1.0f / fmaxf(sqrtf(ss[r]), 1e-12f);
  }
#pragma unroll
  for (int n = 0; n < 4; n++)
#pragma unroll
    for (int r = 0; r < 4; r++)
      h[(size_t)(m0 + 4 * lq + r) * 64 + 16 * n + lm] = f2bf(x[n][r] * ss[r]);
}

// ---------------- output gather for layer slice l ----------------
__global__ void k_out(const float* __restrict__ fu, const float* __restrict__ fi,
                      const unsigned short* __restrict__ h,
                      const int* __restrict__ users, const int* __restrict__ pos,
                      const int* __restrict__ neg, float* __restrict__ out, int l) {
  int t = blockIdx.x * blockDim.x + threadIdx.x;
  if (t >= 3 * NSEL * 64) return;
  int j = t & 63;
  int row = (t >> 6) & (NSEL - 1);
  int grp = t >> 19;  // 6 + 13
  int sr = grp == 0 ? users[row] : (grp == 1 ? pos[row] : neg[row]);
  float v;
  if (grp == 0) v = (l == 0) ? fu[(size_t)sr * 64 + j] : bf2f(h[(size_t)sr * 64 + j]);
  else          v = (l == 0) ? fi[(size_t)sr * 64 + j]
                             : bf2f(h[(size_t)(NU_N + sr) * 64 + j]);
  out[(size_t)grp * NSEL * 256 + (size_t)row * 256 + (size_t)l * 64 + j] = v;
}

// ---------------- host launcher ----------------
extern "C" void kernel_launch(void* const* d_in, const int* in_sizes, int n_in,
                              void* d_out, int out_size, void* d_ws, size_t ws_size,
                              hipStream_t stream) {
  (void)in_sizes; (void)n_in; (void)out_size; (void)ws_size;
  const float* fu = (const float*)d_in[0];
  const float* fi = (const float*)d_in[1];
  const float* W1 = (const float*)d_in[2];
  const float* b1 = (const float*)d_in[3];
  const float* W2 = (const float*)d_in[4];
  const float* b2 = (const float*)d_in[5];
  const int* u_idx = (const int*)d_in[6];
  const int* i_idx = (const int*)d_in[7];
  const int* users = (const int*)d_in[8];
  const int* pos   = (const int*)d_in[9];
  const int* neg   = (const int*)d_in[10];
  float* out = (float*)d_out;

  char* w = (char*)d_ws;
  auto alloc = [&](size_t bytes) { char* p = w; w += (bytes + 255) & ~(size_t)255; return p; };
  unsigned short* h  = (unsigned short*)alloc((size_t)NN_N * 64 * 2);   // users then items
  unsigned short* sb = (unsigned short*)alloc((size_t)NN_N * 64 * 2);   // gathered si/su
  float* csum = (float*)alloc((size_t)NN_N * 4);
  int*   deg  = (int*)alloc((size_t)NN_N * 4);
  float* rdeg = (float*)alloc((size_t)NN_N * 4);
  int*   offs = (int*)alloc((size_t)NN_N * 4);
  int*   cur  = (int*)alloc((size_t)NN_N * 4);
  int*   sums = (int*)alloc((size_t)SCAN_BLOCK * 4);
  int*   nbr  = (int*)alloc((size_t)2 * E_N * 4);
  float* wgt  = (float*)alloc((size_t)2 * E_N * 4);
  unsigned short* w1b = (unsigned short*)alloc((size_t)3 * 4096 * 2);
  unsigned short* w2b = (unsigned short*)alloc((size_t)3 * 4096 * 2);

  // ---- CSR build ----
  hipMemsetAsync(deg, 0, (size_t)NN_N * 4, stream);
  k_deg<<<(E_N + 255) / 256, 256, 0, stream>>>(u_idx, i_idx, deg);
  k_rdeg<<<(NN_N + 255) / 256, 256, 0, stream>>>(deg, rdeg);
  k_scan1<<<SCAN_NB, SCAN_BLOCK, 0, stream>>>(deg, offs, sums);
  k_scan2<<<1, SCAN_BLOCK, 0, stream>>>(sums);
  k_scan3<<<(NN_N + 255) / 256, 256, 0, stream>>>(offs, sums, cur);
  k_fill<<<(E_N + 255) / 256, 256, 0, stream>>>(u_idx, i_idx, rdeg, cur, nbr, wgt);

  // ---- bf16 inputs ----
  k_cvt8<<<(NU_N * 64 / 8 + 255) / 256, 256, 0, stream>>>(fu, h, NU_N * 64);
  k_cvt8<<<(NI_N * 64 / 8 + 255) / 256, 256, 0, stream>>>(fi, h + (size_t)NU_N * 64, NI_N * 64);
  k_cvt8<<<(3 * 4096 / 8 + 255) / 256, 256, 0, stream>>>(W1, w1b, 3 * 4096);
  k_cvt8<<<(3 * 4096 / 8 + 255) / 256, 256, 0, stream>>>(W2, w2b, 3 * 4096);
  k_out<<<(3 * NSEL * 64 + 255) / 256, 256, 0, stream>>>(fu, fi, h, users, pos, neg, out, 0);

  // ---- layers ----
  for (int l = 0; l < 3; l++) {
    k_gather<<<(NN_N * 64 + 255) / 256, 256, 0, stream>>>(h, offs, deg, nbr, wgt, sb, csum);
    k_update<<<((NN_N / 16) * 64 + 255) / 256, 256, 0, stream>>>(
        h, sb, csum, w1b + (size_t)l * 4096, w2b + (size_t)l * 4096,
        b1 + (size_t)l * 64, b2 + (size_t)l * 64);
    k_out<<<(3 * NSEL * 64 + 255) / 256, 256, 0, stream>>>(fu, fi, h, users, pos, neg, out, l + 1);
  }
}

// Round 4
// 382.524 us; speedup vs baseline: 2.2421x; 1.4000x over previous
//
#include <hip/hip_runtime.h>

#define NU_N 100000
#define NI_N 50000
#define NN_N 150000          // NU+NI combined nodes
#define E_N  500000
#define NSEL 8192
#define SCAN_BLOCK 256
#define SCAN_ITEMS 1024
#define SCAN_NB ((NN_N + SCAN_ITEMS - 1) / SCAN_ITEMS)   // 147

typedef short s8v __attribute__((ext_vector_type(8)));
typedef short s4v __attribute__((ext_vector_type(4)));
typedef float f4v __attribute__((ext_vector_type(4)));

__device__ __forceinline__ float bf2f(unsigned short h) {
  union { unsigned u; float f; } v; v.u = ((unsigned)h) << 16; return v.f;
}
__device__ __forceinline__ unsigned short f2bf(float f) {
  union { float f; unsigned u; } v; v.f = f;
  unsigned u = v.u;
  u += 0x7FFFu + ((u >> 16) & 1u);   // round-to-nearest-even
  return (unsigned short)(u >> 16);
}

// ---------------- fp32 -> bf16 bulk convert ----------------
__global__ void k_cvt8(const float* __restrict__ in, unsigned short* __restrict__ out, int n) {
  int t = blockIdx.x * blockDim.x + threadIdx.x;
  int i = t * 8;
  if (i >= n) return;
  float4 a = *(const float4*)(in + i);
  float4 b = *(const float4*)(in + i + 4);
  s8v o;
  o[0] = (short)f2bf(a.x); o[1] = (short)f2bf(a.y);
  o[2] = (short)f2bf(a.z); o[3] = (short)f2bf(a.w);
  o[4] = (short)f2bf(b.x); o[5] = (short)f2bf(b.y);
  o[6] = (short)f2bf(b.z); o[7] = (short)f2bf(b.w);
  *(s8v*)(out + i) = o;
}

// ---------------- degree (combined node id space) ----------------
__global__ void k_deg(const int* __restrict__ u_idx, const int* __restrict__ i_idx,
                      int* __restrict__ deg) {
  int e = blockIdx.x * blockDim.x + threadIdx.x;
  if (e < E_N) {
    atomicAdd(deg + u_idx[e], 1);
    atomicAdd(deg + NU_N + i_idx[e], 1);
  }
}

__global__ void k_rdeg(const int* __restrict__ deg, float* __restrict__ rdeg) {
  int g = blockIdx.x * blockDim.x + threadIdx.x;
  if (g < NN_N) {
    int d = deg[g];
    rdeg[g] = d > 0 ? 1.0f / sqrtf((float)d) : 0.0f;
  }
}

// ---------------- 3-kernel exclusive scan of deg -> offs ----------------
__global__ void k_scan1(const int* __restrict__ deg, int* __restrict__ offs,
                        int* __restrict__ sums) {
  __shared__ int lds[SCAN_BLOCK];
  int b = blockIdx.x, t = threadIdx.x;
  int base = b * SCAN_ITEMS + t * 4;
  int v[4]; int s = 0;
#pragma unroll
  for (int k = 0; k < 4; k++) {
    int idx = base + k;
    v[k] = idx < NN_N ? deg[idx] : 0;
    s += v[k];
  }
  lds[t] = s;
  __syncthreads();
  for (int off = 1; off < SCAN_BLOCK; off <<= 1) {
    int o = t >= off ? lds[t - off] : 0;
    __syncthreads();
    lds[t] += o;
    __syncthreads();
  }
  int run = lds[t] - s;   // exclusive prefix of this thread
#pragma unroll
  for (int k = 0; k < 4; k++) {
    int idx = base + k;
    if (idx < NN_N) offs[idx] = run;
    run += v[k];
  }
  if (t == SCAN_BLOCK - 1) sums[b] = lds[t];
}

__global__ void k_scan2(int* __restrict__ sums) {
  __shared__ int lds[SCAN_BLOCK];
  int t = threadIdx.x;
  int v = t < SCAN_NB ? sums[t] : 0;
  lds[t] = v;
  __syncthreads();
  for (int off = 1; off < SCAN_BLOCK; off <<= 1) {
    int o = t >= off ? lds[t - off] : 0;
    __syncthreads();
    lds[t] += o;
    __syncthreads();
  }
  if (t < SCAN_NB) sums[t] = lds[t] - v;   // exclusive block base
}

__global__ void k_scan3(int* __restrict__ offs, const int* __restrict__ sums,
                        int* __restrict__ cur) {
  int idx = blockIdx.x * blockDim.x + threadIdx.x;
  if (idx < NN_N) {
    int o = offs[idx] + sums[idx >> 10];
    offs[idx] = o;
    cur[idx] = o;
  }
}

// ---------------- CSR fill (both directions, combined id space) ----------------
__global__ void k_fill(const int* __restrict__ u_idx, const int* __restrict__ i_idx,
                       int* __restrict__ cur, int* __restrict__ nbr) {
  int e = blockIdx.x * blockDim.x + threadIdx.x;
  if (e >= E_N) return;
  int u = u_idx[e], gi = NU_N + i_idx[e];
  int s1 = atomicAdd(cur + u, 1);
  nbr[s1] = gi;
  int s2 = atomicAdd(cur + gi, 1);
  nbr[s2] = u;
}

// ---------------- weighted neighbor gather, 8 neighbors in flight per wave ----------------
// s[g] = rdeg[g] * sum_nb rdeg[nb]*h[nb];  csum[g] = rdeg[g] * sum_nb rdeg[nb]
__global__ void k_gather(const unsigned short* __restrict__ h,
                         const int* __restrict__ offs, const int* __restrict__ deg,
                         const int* __restrict__ nbr, const float* __restrict__ rdeg,
                         unsigned short* __restrict__ s, float* __restrict__ csum) {
  int wid = (blockIdx.x * blockDim.x + threadIdx.x) >> 6;
  if (wid >= NN_N) return;
  int lane = threadIdx.x & 63;
  int q = lane >> 3, m = lane & 7;       // q: neighbor slot, m: 8-bf16 chunk within row
  int k0 = offs[wid], d = deg[wid];
  float acc[8] = {0.f, 0.f, 0.f, 0.f, 0.f, 0.f, 0.f, 0.f};
  float c = 0.f;
  for (int t = q; t < d; t += 8) {
    int nb = nbr[k0 + t];                // uniform within 8-lane group
    float w = rdeg[nb];
    s8v v = *(const s8v*)(h + (size_t)nb * 64 + m * 8);
#pragma unroll
    for (int j = 0; j < 8; j++) acc[j] += w * bf2f((unsigned short)v[j]);
    c += w;
  }
#pragma unroll
  for (int off = 8; off < 64; off <<= 1) {
#pragma unroll
    for (int j = 0; j < 8; j++) acc[j] += __shfl_xor(acc[j], off);
    c += __shfl_xor(c, off);
  }
  float rw = rdeg[wid];
  if (q == 0) {
    s8v o;
#pragma unroll
    for (int j = 0; j < 8; j++) o[j] = (short)f2bf(acc[j] * rw);
    *(s8v*)(s + (size_t)wid * 64 + m * 8) = o;
    if (m == 0) csum[wid] = c * rw;
  }
}

// ---------------- B-fragment loader (W is 64x64 bf16, row-major [k][n]) ----------------
// mfma_f32_16x16x32_bf16 B layout: n = lane&15, k = 8*(lane>>4)+j
__device__ __forceinline__ void load_bfrags(const unsigned short* __restrict__ wb, s8v bf[4][2]) {
  int lane = threadIdx.x & 63;
  int lm = lane & 15, lq = lane >> 4;
#pragma unroll
  for (int n = 0; n < 4; n++)
#pragma unroll
    for (int kh = 0; kh < 2; kh++) {
      s8v f;
#pragma unroll
      for (int j = 0; j < 8; j++)
        f[j] = (short)wb[(32 * kh + 8 * lq + j) * 64 + 16 * n + lm];
      bf[n][kh] = f;
    }
}

// ---------------- fused node update ----------------
// h = l2norm(leaky( (h+s)@W1 + (1+c)b1 + (h*s)@W2 + c*b2 ))   (in place, per 16-row tile)
__global__ void k_update(unsigned short* __restrict__ h, const unsigned short* __restrict__ s,
                         const float* __restrict__ csum,
                         const unsigned short* __restrict__ w1b, const unsigned short* __restrict__ w2b,
                         const float* __restrict__ b1, const float* __restrict__ b2) {
  s8v f1[4][2], f2w[4][2];
  load_bfrags(w1b, f1);
  load_bfrags(w2b, f2w);
  int lane = threadIdx.x & 63;
  int lm = lane & 15, lq = lane >> 4;
  int tile = (blockIdx.x * blockDim.x + threadIdx.x) >> 6;
  if (tile >= NN_N / 16) return;
  int m0 = tile << 4;
  size_t rowo = (size_t)(m0 + lm) * 64;
  s8v h0 = *(const s8v*)(h + rowo + 8 * lq);
  s8v h1 = *(const s8v*)(h + rowo + 32 + 8 * lq);
  s8v s0 = *(const s8v*)(s + rowo + 8 * lq);
  s8v s1 = *(const s8v*)(s + rowo + 32 + 8 * lq);
  s8v a10, a11, a20, a21;
#pragma unroll
  for (int j = 0; j < 8; j++) {
    float hv0 = bf2f((unsigned short)h0[j]), sv0 = bf2f((unsigned short)s0[j]);
    float hv1 = bf2f((unsigned short)h1[j]), sv1 = bf2f((unsigned short)s1[j]);
    a10[j] = (short)f2bf(hv0 + sv0); a20[j] = (short)f2bf(hv0 * sv0);
    a11[j] = (short)f2bf(hv1 + sv1); a21[j] = (short)f2bf(hv1 * sv1);
  }
  f4v c[4];
#pragma unroll
  for (int n = 0; n < 4; n++) c[n] = (f4v){0.f, 0.f, 0.f, 0.f};
#pragma unroll
  for (int n = 0; n < 4; n++) {
    c[n] = __builtin_amdgcn_mfma_f32_16x16x32_bf16(a10, f1[n][0], c[n], 0, 0, 0);
    c[n] = __builtin_amdgcn_mfma_f32_16x16x32_bf16(a11, f1[n][1], c[n], 0, 0, 0);
    c[n] = __builtin_amdgcn_mfma_f32_16x16x32_bf16(a20, f2w[n][0], c[n], 0, 0, 0);
    c[n] = __builtin_amdgcn_mfma_f32_16x16x32_bf16(a21, f2w[n][1], c[n], 0, 0, 0);
  }
  float b1c[4], b2c[4];
#pragma unroll
  for (int n = 0; n < 4; n++) { b1c[n] = b1[16 * n + lm]; b2c[n] = b2[16 * n + lm]; }
  float cm[4];
#pragma unroll
  for (int r = 0; r < 4; r++) cm[r] = csum[m0 + 4 * lq + r];
  float x[4][4], ss[4] = {0.f, 0.f, 0.f, 0.f};
#pragma unroll
  for (int n = 0; n < 4; n++)
#pragma unroll
    for (int r = 0; r < 4; r++) {
      float v = c[n][r] + b1c[n] + cm[r] * (b1c[n] + b2c[n]);
      v = v > 0.0f ? v : 0.2f * v;
      x[n][r] = v;
      ss[r] += v * v;
    }
#pragma unroll
  for (int r = 0; r < 4; r++) {
#pragma unroll
    for (int off = 1; off < 16; off <<= 1) ss[r] += __shfl_xor(ss[r], off);
    ss[r] = 1.0f / fmaxf(sqrtf(ss[r]), 1e-12f);
  }
#pragma unroll
  for (int n = 0; n < 4; n++)
#pragma unroll
    for (int r = 0; r < 4; r++)
      h[(size_t)(m0 + 4 * lq + r) * 64 + 16 * n + lm] = f2bf(x[n][r] * ss[r]);
}

// ---------------- output gather for layer slice l (4 cols/thread) ----------------
__global__ void k_out(const float* __restrict__ fu, const float* __restrict__ fi,
                      const unsigned short* __restrict__ h,
                      const int* __restrict__ users, const int* __restrict__ pos,
                      const int* __restrict__ neg, float* __restrict__ out, int l) {
  int t = blockIdx.x * blockDim.x + threadIdx.x;
  if (t >= 3 * NSEL * 16) return;
  int j4 = (t & 15) * 4;
  int row = (t >> 4) & (NSEL - 1);
  int grp = t >> 17;  // 4 + 13
  int sr = grp == 0 ? users[row] : (grp == 1 ? pos[row] : neg[row]);
  float4 v;
  if (l == 0) {
    const float* f = grp == 0 ? fu : fi;
    v = *(const float4*)(f + (size_t)sr * 64 + j4);
  } else {
    const unsigned short* hh = h + (size_t)(grp == 0 ? sr : NU_N + sr) * 64 + j4;
    s4v x = *(const s4v*)hh;
    v.x = bf2f((unsigned short)x[0]); v.y = bf2f((unsigned short)x[1]);
    v.z = bf2f((unsigned short)x[2]); v.w = bf2f((unsigned short)x[3]);
  }
  *(float4*)(out + (size_t)grp * NSEL * 256 + (size_t)row * 256 + (size_t)l * 64 + j4) = v;
}

// ---------------- host launcher ----------------
extern "C" void kernel_launch(void* const* d_in, const int* in_sizes, int n_in,
                              void* d_out, int out_size, void* d_ws, size_t ws_size,
                              hipStream_t stream) {
  (void)in_sizes; (void)n_in; (void)out_size; (void)ws_size;
  const float* fu = (const float*)d_in[0];
  const float* fi = (const float*)d_in[1];
  const float* W1 = (const float*)d_in[2];
  const float* b1 = (const float*)d_in[3];
  const float* W2 = (const float*)d_in[4];
  const float* b2 = (const float*)d_in[5];
  const int* u_idx = (const int*)d_in[6];
  const int* i_idx = (const int*)d_in[7];
  const int* users = (const int*)d_in[8];
  const int* pos   = (const int*)d_in[9];
  const int* neg   = (const int*)d_in[10];
  float* out = (float*)d_out;

  char* w = (char*)d_ws;
  auto alloc = [&](size_t bytes) { char* p = w; w += (bytes + 255) & ~(size_t)255; return p; };
  unsigned short* h  = (unsigned short*)alloc((size_t)NN_N * 64 * 2);   // users then items
  unsigned short* sb = (unsigned short*)alloc((size_t)NN_N * 64 * 2);   // gathered si/su
  float* csum = (float*)alloc((size_t)NN_N * 4);
  int*   deg  = (int*)alloc((size_t)NN_N * 4);
  float* rdeg = (float*)alloc((size_t)NN_N * 4);
  int*   offs = (int*)alloc((size_t)NN_N * 4);
  int*   cur  = (int*)alloc((size_t)NN_N * 4);
  int*   sums = (int*)alloc((size_t)SCAN_BLOCK * 4);
  int*   nbr  = (int*)alloc((size_t)2 * E_N * 4);
  unsigned short* w1b = (unsigned short*)alloc((size_t)3 * 4096 * 2);
  unsigned short* w2b = (unsigned short*)alloc((size_t)3 * 4096 * 2);

  // ---- CSR build ----
  hipMemsetAsync(deg, 0, (size_t)NN_N * 4, stream);
  k_deg<<<(E_N + 255) / 256, 256, 0, stream>>>(u_idx, i_idx, deg);
  k_rdeg<<<(NN_N + 255) / 256, 256, 0, stream>>>(deg, rdeg);
  k_scan1<<<SCAN_NB, SCAN_BLOCK, 0, stream>>>(deg, offs, sums);
  k_scan2<<<1, SCAN_BLOCK, 0, stream>>>(sums);
  k_scan3<<<(NN_N + 255) / 256, 256, 0, stream>>>(offs, sums, cur);
  k_fill<<<(E_N + 255) / 256, 256, 0, stream>>>(u_idx, i_idx, cur, nbr);

  // ---- bf16 inputs ----
  k_cvt8<<<(NU_N * 64 / 8 + 255) / 256, 256, 0, stream>>>(fu, h, NU_N * 64);
  k_cvt8<<<(NI_N * 64 / 8 + 255) / 256, 256, 0, stream>>>(fi, h + (size_t)NU_N * 64, NI_N * 64);
  k_cvt8<<<(3 * 4096 / 8 + 255) / 256, 256, 0, stream>>>(W1, w1b, 3 * 4096);
  k_cvt8<<<(3 * 4096 / 8 + 255) / 256, 256, 0, stream>>>(W2, w2b, 3 * 4096);
  k_out<<<(3 * NSEL * 16 + 255) / 256, 256, 0, stream>>>(fu, fi, h, users, pos, neg, out, 0);

  // ---- layers ----
  for (int l = 0; l < 3; l++) {
    k_gather<<<(NN_N * 64 + 255) / 256, 256, 0, stream>>>(h, offs, deg, nbr, rdeg, sb, csum);
    k_update<<<((NN_N / 16) * 64 + 255) / 256, 256, 0, stream>>>(
        h, sb, csum, w1b + (size_t)l * 4096, w2b + (size_t)l * 4096,
        b1 + (size_t)l * 64, b2 + (size_t)l * 64);
    k_out<<<(3 * NSEL * 16 + 255) / 256, 256, 0, stream>>>(fu, fi, h, users, pos, neg, out, l + 1);
  }
}

// Round 6
// 328.002 us; speedup vs baseline: 2.6148x; 1.1662x over previous
//
#include <hip/hip_runtime.h>

#define NU_N 100000
#define NI_N 50000
#define NN_N 150000          // NU+NI combined nodes
#define E_N  500000
#define NSEL 8192
#define SCAN_BLOCK 256
#define SCAN_ITEMS 1024
#define SCAN_NB ((NN_N + SCAN_ITEMS - 1) / SCAN_ITEMS)   // 147

typedef short s8v __attribute__((ext_vector_type(8)));
typedef short s4v __attribute__((ext_vector_type(4)));
typedef float f4v __attribute__((ext_vector_type(4)));

__device__ __forceinline__ float bf2f(unsigned short h) {
  union { unsigned u; float f; } v; v.u = ((unsigned)h) << 16; return v.f;
}
__device__ __forceinline__ unsigned short f2bf(float f) {
  union { float f; unsigned u; } v; v.f = f;
  unsigned u = v.u;
  u += 0x7FFFu + ((u >> 16) & 1u);   // round-to-nearest-even
  return (unsigned short)(u >> 16);
}

// ---------------- fp32 -> bf16 bulk convert ----------------
__global__ void k_cvt8(const float* __restrict__ in, unsigned short* __restrict__ out, int n) {
  int t = blockIdx.x * blockDim.x + threadIdx.x;
  int i = t * 8;
  if (i >= n) return;
  float4 a = *(const float4*)(in + i);
  float4 b = *(const float4*)(in + i + 4);
  s8v o;
  o[0] = (short)f2bf(a.x); o[1] = (short)f2bf(a.y);
  o[2] = (short)f2bf(a.z); o[3] = (short)f2bf(a.w);
  o[4] = (short)f2bf(b.x); o[5] = (short)f2bf(b.y);
  o[6] = (short)f2bf(b.z); o[7] = (short)f2bf(b.w);
  *(s8v*)(out + i) = o;
}

// ---------------- degree + per-edge rank (combined node id space) ----------------
__global__ void k_deg(const int* __restrict__ u_idx, const int* __restrict__ i_idx,
                      int* __restrict__ deg, int* __restrict__ rank_u, int* __restrict__ rank_i) {
  int e = blockIdx.x * blockDim.x + threadIdx.x;
  if (e < E_N) {
    rank_u[e] = atomicAdd(deg + u_idx[e], 1);
    rank_i[e] = atomicAdd(deg + NU_N + i_idx[e], 1);
  }
}

__global__ void k_rdeg(const int* __restrict__ deg, float* __restrict__ rdeg) {
  int g = blockIdx.x * blockDim.x + threadIdx.x;
  if (g < NN_N) {
    int d = deg[g];
    rdeg[g] = d > 0 ? 1.0f / sqrtf((float)d) : 0.0f;
  }
}

// ---------------- 3-kernel exclusive scan of deg -> offs ----------------
__global__ void k_scan1(const int* __restrict__ deg, int* __restrict__ offs,
                        int* __restrict__ sums) {
  __shared__ int lds[SCAN_BLOCK];
  int b = blockIdx.x, t = threadIdx.x;
  int base = b * SCAN_ITEMS + t * 4;
  int v[4]; int s = 0;
#pragma unroll
  for (int k = 0; k < 4; k++) {
    int idx = base + k;
    v[k] = idx < NN_N ? deg[idx] : 0;
    s += v[k];
  }
  lds[t] = s;
  __syncthreads();
  for (int off = 1; off < SCAN_BLOCK; off <<= 1) {
    int o = t >= off ? lds[t - off] : 0;
    __syncthreads();
    lds[t] += o;
    __syncthreads();
  }
  int run = lds[t] - s;   // exclusive prefix of this thread
#pragma unroll
  for (int k = 0; k < 4; k++) {
    int idx = base + k;
    if (idx < NN_N) offs[idx] = run;
    run += v[k];
  }
  if (t == SCAN_BLOCK - 1) sums[b] = lds[t];
}

__global__ void k_scan2(int* __restrict__ sums) {
  __shared__ int lds[SCAN_BLOCK];
  int t = threadIdx.x;
  int v = t < SCAN_NB ? sums[t] : 0;
  lds[t] = v;
  __syncthreads();
  for (int off = 1; off < SCAN_BLOCK; off <<= 1) {
    int o = t >= off ? lds[t - off] : 0;
    __syncthreads();
    lds[t] += o;
    __syncthreads();
  }
  if (t < SCAN_NB) sums[t] = lds[t] - v;   // exclusive block base
}

__global__ void k_scan3(int* __restrict__ offs, const int* __restrict__ sums) {
  int idx = blockIdx.x * blockDim.x + threadIdx.x;
  if (idx < NN_N) offs[idx] += sums[idx >> 10];
}

// ---------------- CSR fill, atomics-free (rank precomputed) ----------------
// user segments -> nbrU (u16 item ids, slots [0,E)); item segments -> nbrI (u32 user ids)
__global__ void k_fill(const int* __restrict__ u_idx, const int* __restrict__ i_idx,
                       const int* __restrict__ rank_u, const int* __restrict__ rank_i,
                       const int* __restrict__ offs,
                       unsigned short* __restrict__ nbrU, int* __restrict__ nbrI) {
  int e = blockIdx.x * blockDim.x + threadIdx.x;
  if (e >= E_N) return;
  int u = u_idx[e], it = i_idx[e];
  nbrU[offs[u] + rank_u[e]] = (unsigned short)it;
  nbrI[(offs[NU_N + it] - E_N) + rank_i[e]] = u;
}

// ---------------- weighted neighbor gather ----------------
// s[g] = rdeg[g] * sum_nb rdeg[nb]*h[nb];  csum[g] = rdeg[g] * sum_nb rdeg[nb]
// 8 neighbor slots/wave; ids+weights preloaded once per wave, broadcast via shfl.
// CRITICAL: main loop trip count is wave-uniform so every shfl source lane is
// active (bpermute from an exited lane is undefined -> round-5 bug). Lanes with
// t >= d source the preloaded zeros and contribute exactly 0.
__global__ void k_gather(const unsigned short* __restrict__ h,
                         const int* __restrict__ offs, const int* __restrict__ deg,
                         const unsigned short* __restrict__ nbrU, const int* __restrict__ nbrI,
                         const float* __restrict__ rdeg,
                         unsigned short* __restrict__ s, float* __restrict__ csum) {
  int wid = (blockIdx.x * blockDim.x + threadIdx.x) >> 6;
  if (wid >= NN_N) return;
  int lane = threadIdx.x & 63;
  int q = lane >> 3, m = lane & 7;       // q: neighbor slot, m: 8-bf16 chunk within row
  int d = deg[wid];
  bool isU = wid < NU_N;
  int k0 = isU ? offs[wid] : offs[wid] - E_N;
  // preload up to 64 neighbor ids + weights; zero-filled beyond d
  int myid = 0;
  float myw = 0.0f;
  if (lane < d) {
    myid = isU ? (NU_N + (int)nbrU[k0 + lane]) : nbrI[k0 + lane];
    myw = rdeg[myid];
  }
  float acc[8] = {0.f, 0.f, 0.f, 0.f, 0.f, 0.f, 0.f, 0.f};
  float c = 0.f;
  int dc = d < 64 ? d : 64;
  int niter = (dc + 7) >> 3;             // UNIFORM across the wave
  for (int i = 0; i < niter; i++) {
    int t = (i << 3) + q;                // t <= 63 always
    int nb  = __shfl(myid, t);           // 0 when t >= d (source lane active, holds 0)
    float w = __shfl(myw, t);            // 0 when t >= d
    s8v v = *(const s8v*)(h + (size_t)nb * 64 + m * 8);
#pragma unroll
    for (int j = 0; j < 8; j++) acc[j] += w * bf2f((unsigned short)v[j]);
    c += w;
  }
  for (int t = 64 + q; t < d; t += 8) {  // fallback (no shfl -> divergence safe)
    int nb = isU ? (NU_N + (int)nbrU[k0 + t]) : nbrI[k0 + t];
    float w = rdeg[nb];
    s8v v = *(const s8v*)(h + (size_t)nb * 64 + m * 8);
#pragma unroll
    for (int j = 0; j < 8; j++) acc[j] += w * bf2f((unsigned short)v[j]);
    c += w;
  }
#pragma unroll
  for (int off = 8; off < 64; off <<= 1) {
#pragma unroll
    for (int j = 0; j < 8; j++) acc[j] += __shfl_xor(acc[j], off);
    c += __shfl_xor(c, off);
  }
  float rw = rdeg[wid];
  if (q == 0) {
    s8v o;
#pragma unroll
    for (int j = 0; j < 8; j++) o[j] = (short)f2bf(acc[j] * rw);
    *(s8v*)(s + (size_t)wid * 64 + m * 8) = o;
    if (m == 0) csum[wid] = c * rw;
  }
}

// ---------------- B-fragment loader (W is 64x64 bf16, row-major [k][n]) ----------------
// mfma_f32_16x16x32_bf16 B layout: n = lane&15, k = 8*(lane>>4)+j
__device__ __forceinline__ void load_bfrags(const unsigned short* __restrict__ wb, s8v bf[4][2]) {
  int lane = threadIdx.x & 63;
  int lm = lane & 15, lq = lane >> 4;
#pragma unroll
  for (int n = 0; n < 4; n++)
#pragma unroll
    for (int kh = 0; kh < 2; kh++) {
      s8v f;
#pragma unroll
      for (int j = 0; j < 8; j++)
        f[j] = (short)wb[(32 * kh + 8 * lq + j) * 64 + 16 * n + lm];
      bf[n][kh] = f;
    }
}

// ---------------- fused node update ----------------
// h = l2norm(leaky( (h+s)@W1 + (1+c)b1 + (h*s)@W2 + c*b2 ))   (in place, per 16-row tile)
__global__ void k_update(unsigned short* __restrict__ h, const unsigned short* __restrict__ s,
                         const float* __restrict__ csum,
                         const unsigned short* __restrict__ w1b, const unsigned short* __restrict__ w2b,
                         const float* __restrict__ b1, const float* __restrict__ b2) {
  s8v f1[4][2], f2w[4][2];
  load_bfrags(w1b, f1);
  load_bfrags(w2b, f2w);
  int lane = threadIdx.x & 63;
  int lm = lane & 15, lq = lane >> 4;
  int tile = (blockIdx.x * blockDim.x + threadIdx.x) >> 6;
  if (tile >= NN_N / 16) return;
  int m0 = tile << 4;
  size_t rowo = (size_t)(m0 + lm) * 64;
  s8v h0 = *(const s8v*)(h + rowo + 8 * lq);
  s8v h1 = *(const s8v*)(h + rowo + 32 + 8 * lq);
  s8v s0 = *(const s8v*)(s + rowo + 8 * lq);
  s8v s1 = *(const s8v*)(s + rowo + 32 + 8 * lq);
  s8v a10, a11, a20, a21;
#pragma unroll
  for (int j = 0; j < 8; j++) {
    float hv0 = bf2f((unsigned short)h0[j]), sv0 = bf2f((unsigned short)s0[j]);
    float hv1 = bf2f((unsigned short)h1[j]), sv1 = bf2f((unsigned short)s1[j]);
    a10[j] = (short)f2bf(hv0 + sv0); a20[j] = (short)f2bf(hv0 * sv0);
    a11[j] = (short)f2bf(hv1 + sv1); a21[j] = (short)f2bf(hv1 * sv1);
  }
  f4v c[4];
#pragma unroll
  for (int n = 0; n < 4; n++) c[n] = (f4v){0.f, 0.f, 0.f, 0.f};
#pragma unroll
  for (int n = 0; n < 4; n++) {
    c[n] = __builtin_amdgcn_mfma_f32_16x16x32_bf16(a10, f1[n][0], c[n], 0, 0, 0);
    c[n] = __builtin_amdgcn_mfma_f32_16x16x32_bf16(a11, f1[n][1], c[n], 0, 0, 0);
    c[n] = __builtin_amdgcn_mfma_f32_16x16x32_bf16(a20, f2w[n][0], c[n], 0, 0, 0);
    c[n] = __builtin_amdgcn_mfma_f32_16x16x32_bf16(a21, f2w[n][1], c[n], 0, 0, 0);
  }
  float b1c[4], b2c[4];
#pragma unroll
  for (int n = 0; n < 4; n++) { b1c[n] = b1[16 * n + lm]; b2c[n] = b2[16 * n + lm]; }
  float cm[4];
#pragma unroll
  for (int r = 0; r < 4; r++) cm[r] = csum[m0 + 4 * lq + r];
  float x[4][4], ss[4] = {0.f, 0.f, 0.f, 0.f};
#pragma unroll
  for (int n = 0; n < 4; n++)
#pragma unroll
    for (int r = 0; r < 4; r++) {
      float v = c[n][r] + b1c[n] + cm[r] * (b1c[n] + b2c[n]);
      v = v > 0.0f ? v : 0.2f * v;
      x[n][r] = v;
      ss[r] += v * v;
    }
#pragma unroll
  for (int r = 0; r < 4; r++) {
#pragma unroll
    for (int off = 1; off < 16; off <<= 1) ss[r] += __shfl_xor(ss[r], off);
    ss[r] = 1.0f / fmaxf(sqrtf(ss[r]), 1e-12f);
  }
#pragma unroll
  for (int n = 0; n < 4; n++)
#pragma unroll
    for (int r = 0; r < 4; r++)
      h[(size_t)(m0 + 4 * lq + r) * 64 + 16 * n + lm] = f2bf(x[n][r] * ss[r]);
}

// ---------------- output gather for layer slice l (4 cols/thread) ----------------
__global__ void k_out(const float* __restrict__ fu, const float* __restrict__ fi,
                      const unsigned short* __restrict__ h,
                      const int* __restrict__ users, const int* __restrict__ pos,
                      const int* __restrict__ neg, float* __restrict__ out, int l) {
  int t = blockIdx.x * blockDim.x + threadIdx.x;
  if (t >= 3 * NSEL * 16) return;
  int j4 = (t & 15) * 4;
  int row = (t >> 4) & (NSEL - 1);
  int grp = t >> 17;  // 4 + 13
  int sr = grp == 0 ? users[row] : (grp == 1 ? pos[row] : neg[row]);
  float4 v;
  if (l == 0) {
    const float* f = grp == 0 ? fu : fi;
    v = *(const float4*)(f + (size_t)sr * 64 + j4);
  } else {
    const unsigned short* hh = h + (size_t)(grp == 0 ? sr : NU_N + sr) * 64 + j4;
    s4v x = *(const s4v*)hh;
    v.x = bf2f((unsigned short)x[0]); v.y = bf2f((unsigned short)x[1]);
    v.z = bf2f((unsigned short)x[2]); v.w = bf2f((unsigned short)x[3]);
  }
  *(float4*)(out + (size_t)grp * NSEL * 256 + (size_t)row * 256 + (size_t)l * 64 + j4) = v;
}

// ---------------- host launcher ----------------
extern "C" void kernel_launch(void* const* d_in, const int* in_sizes, int n_in,
                              void* d_out, int out_size, void* d_ws, size_t ws_size,
                              hipStream_t stream) {
  (void)in_sizes; (void)n_in; (void)out_size; (void)ws_size;
  const float* fu = (const float*)d_in[0];
  const float* fi = (const float*)d_in[1];
  const float* W1 = (const float*)d_in[2];
  const float* b1 = (const float*)d_in[3];
  const float* W2 = (const float*)d_in[4];
  const float* b2 = (const float*)d_in[5];
  const int* u_idx = (const int*)d_in[6];
  const int* i_idx = (const int*)d_in[7];
  const int* users = (const int*)d_in[8];
  const int* pos   = (const int*)d_in[9];
  const int* neg   = (const int*)d_in[10];
  float* out = (float*)d_out;

  char* w = (char*)d_ws;
  auto alloc = [&](size_t bytes) { char* p = w; w += (bytes + 255) & ~(size_t)255; return p; };
  unsigned short* h  = (unsigned short*)alloc((size_t)NN_N * 64 * 2);   // users then items
  unsigned short* sb = (unsigned short*)alloc((size_t)NN_N * 64 * 2);   // gathered si/su
  float* csum = (float*)alloc((size_t)NN_N * 4);
  int*   deg  = (int*)alloc((size_t)NN_N * 4);
  float* rdeg = (float*)alloc((size_t)NN_N * 4);
  int*   offs = (int*)alloc((size_t)NN_N * 4);
  int*   sums = (int*)alloc((size_t)SCAN_BLOCK * 4);
  int*   rank_u = (int*)alloc((size_t)E_N * 4);
  int*   rank_i = (int*)alloc((size_t)E_N * 4);
  unsigned short* nbrU = (unsigned short*)alloc((size_t)E_N * 2);
  int*   nbrI = (int*)alloc((size_t)E_N * 4);
  unsigned short* w1b = (unsigned short*)alloc((size_t)3 * 4096 * 2);
  unsigned short* w2b = (unsigned short*)alloc((size_t)3 * 4096 * 2);

  // ---- CSR build ----
  hipMemsetAsync(deg, 0, (size_t)NN_N * 4, stream);
  k_deg<<<(E_N + 255) / 256, 256, 0, stream>>>(u_idx, i_idx, deg, rank_u, rank_i);
  k_rdeg<<<(NN_N + 255) / 256, 256, 0, stream>>>(deg, rdeg);
  k_scan1<<<SCAN_NB, SCAN_BLOCK, 0, stream>>>(deg, offs, sums);
  k_scan2<<<1, SCAN_BLOCK, 0, stream>>>(sums);
  k_scan3<<<(NN_N + 255) / 256, 256, 0, stream>>>(offs, sums);
  k_fill<<<(E_N + 255) / 256, 256, 0, stream>>>(u_idx, i_idx, rank_u, rank_i, offs, nbrU, nbrI);

  // ---- bf16 inputs ----
  k_cvt8<<<(NU_N * 64 / 8 + 255) / 256, 256, 0, stream>>>(fu, h, NU_N * 64);
  k_cvt8<<<(NI_N * 64 / 8 + 255) / 256, 256, 0, stream>>>(fi, h + (size_t)NU_N * 64, NI_N * 64);
  k_cvt8<<<(3 * 4096 / 8 + 255) / 256, 256, 0, stream>>>(W1, w1b, 3 * 4096);
  k_cvt8<<<(3 * 4096 / 8 + 255) / 256, 256, 0, stream>>>(W2, w2b, 3 * 4096);
  k_out<<<(3 * NSEL * 16 + 255) / 256, 256, 0, stream>>>(fu, fi, h, users, pos, neg, out, 0);

  // ---- layers ----
  for (int l = 0; l < 3; l++) {
    k_gather<<<(NN_N * 64 + 255) / 256, 256, 0, stream>>>(h, offs, deg, nbrU, nbrI, rdeg, sb, csum);
    k_update<<<((NN_N / 16) * 64 + 255) / 256, 256, 0, stream>>>(
        h, sb, csum, w1b + (size_t)l * 4096, w2b + (size_t)l * 4096,
        b1 + (size_t)l * 64, b2 + (size_t)l * 64);
    k_out<<<(3 * NSEL * 16 + 255) / 256, 256, 0, stream>>>(fu, fi, h, users, pos, neg, out, l + 1);
  }
}